// Round 11
// baseline (288.450 us; speedup 1.0000x reference)
//
#include <hip/hip_runtime.h>

// B=2,H=16,L=2048,D=64 attention, outputs (out[B,H,L,D], score[B,H,L,L]) fp32.
// Floor: write score/out 554MB + read QKV ~50MB ~ 90us at 6.7 TB/s.
//
// v8 = v7 with nontemporal hints REMOVED (single-variable change).
// Rationale: all 6.7 TB/s write datapoints on this chip are plain stores
// through L2 write-back; NT (L2-bypass) is the prime suspect for the ~2x
// effective store-BW deficit (537MB @ ~3.4 TB/s). Contiguity fix (v7) gave
// only +8%, so the store *pattern* is fine -- the *path* is the variable.

#define L_ 2048
#define D_ 64
#define BH_ 32
#define NKT 32

typedef __attribute__((ext_vector_type(8))) short bf16x8;
typedef __attribute__((ext_vector_type(4))) float f32x4;

__device__ __forceinline__ unsigned short f2bf(float f) {
  unsigned u = __builtin_bit_cast(unsigned, f);
  u = (u + 0x7FFFu + ((u >> 16) & 1u)) >> 16;  // RNE
  return (unsigned short)u;
}
__device__ __forceinline__ float bf2f(unsigned short h) {
  unsigned u = ((unsigned)h) << 16;
  return __builtin_bit_cast(float, u);
}
__device__ __forceinline__ void gload_lds16(const void* g, void* l) {
  __builtin_amdgcn_global_load_lds((const __attribute__((address_space(1))) void*)g,
                                   (__attribute__((address_space(3))) void*)l, 16, 0, 0);
}
#define BAR() asm volatile("s_barrier" ::: "memory")

// prep: per 64x64 tile (1024 tiles = bh*32+kt):
//   K -> bf16 fragment-linear tile: el off = (t*2+h)*512 + lg*128 + lc*8 + j
//   V -> VT (transpose) in the same fragment-linear layout (rows=d, cols=k).
// Also zeroes colsum (blocks 0..63).
__global__ void prep(const float* __restrict__ k, const float* __restrict__ v,
                     unsigned short* __restrict__ wkf, unsigned short* __restrict__ wvf,
                     float* __restrict__ colsum) {
  __shared__ unsigned short t_[64][65];
  const int bid = blockIdx.x, tid = threadIdx.x;

  if (bid < 64) {
    float* cz = colsum + bid * 1024;
    for (int i = tid; i < 1024; i += 256) cz[i] = 0.0f;
  }

  // K tile -> fragment layout
  const float* ks = k + (size_t)bid * 64 * D_;
  unsigned short* kd = wkf + (size_t)bid * 4096;
#pragma unroll
  for (int it = 0; it < 2; ++it) {
    int e8 = it * 256 + tid;      // [0,512)
    int r = e8 >> 3;              // row 0..63
    int c0 = (e8 & 7) * 8;        // col 0,8,..,56
    float4 f0 = *reinterpret_cast<const float4*>(ks + r * D_ + c0);
    float4 f1 = *reinterpret_cast<const float4*>(ks + r * D_ + c0 + 4);
    int t = r >> 4, lc = r & 15, h = c0 >> 5, lg = (c0 & 31) >> 3;
    unsigned short* p = kd + (t * 2 + h) * 512 + lg * 128 + lc * 8;
    ushort4 u0{f2bf(f0.x), f2bf(f0.y), f2bf(f0.z), f2bf(f0.w)};
    ushort4 u1{f2bf(f1.x), f2bf(f1.y), f2bf(f1.z), f2bf(f1.w)};
    *reinterpret_cast<ushort4*>(p) = u0;
    *reinterpret_cast<ushort4*>(p + 4) = u1;
  }

  // V tile -> LDS transpose -> fragment layout (rows=d, cols=k)
  const float* vs = v + (size_t)bid * 64 * D_;
#pragma unroll
  for (int it = 0; it < 4; ++it) {
    int e4 = tid + it * 256;
    int r = e4 >> 4, c = (e4 & 15) << 2;
    float4 f = *reinterpret_cast<const float4*>(vs + r * D_ + c);
    t_[r][c + 0] = f2bf(f.x);
    t_[r][c + 1] = f2bf(f.y);
    t_[r][c + 2] = f2bf(f.z);
    t_[r][c + 3] = f2bf(f.w);
  }
  __syncthreads();
  unsigned short* vd = wvf + (size_t)bid * 4096;
#pragma unroll
  for (int it = 0; it < 2; ++it) {
    int e8 = it * 256 + tid;
    int d = e8 >> 3;             // output row (d-dim)
    int k0 = (e8 & 7) * 8;       // output col (k within tile)
    int t = d >> 4, lc = d & 15, h = k0 >> 5, lg = (k0 & 31) >> 3;
    ushort4 u0{t_[k0 + 0][d], t_[k0 + 1][d], t_[k0 + 2][d], t_[k0 + 3][d]};
    ushort4 u1{t_[k0 + 4][d], t_[k0 + 5][d], t_[k0 + 6][d], t_[k0 + 7][d]};
    unsigned short* p = vd + (t * 2 + h) * 512 + lg * 128 + lc * 8;
    *reinterpret_cast<ushort4*>(p) = u0;
    *reinterpret_cast<ushort4*>(p + 4) = u1;
  }
}

__launch_bounds__(256, 4)
__global__ void attn_main(const float* __restrict__ qf,
                          const unsigned short* __restrict__ wkf,
                          const unsigned short* __restrict__ wvf,
                          float* __restrict__ outp,
                          float* __restrict__ score,
                          float* __restrict__ colsum) {
  __shared__ __align__(16) unsigned short kb[2][4096];  // staged K tile dbuf; reused as O stage
  __shared__ __align__(16) unsigned short ps[4][1024];  // per-wave 16x64 bf16 swizzled
  __shared__ float cs_lds[2048];                        // block-local column sums

  const int tid = threadIdx.x;
  const int w = tid >> 6, lane = tid & 63;
  const int lg = lane >> 4, lc = lane & 15;

  // XCD-chunked swizzle: 1024 blocks -> 128 consecutive per XCD (4 bh per XCD)
  const int bid = (blockIdx.x & 7) * 128 + (blockIdx.x >> 3);
  const int bh = bid >> 5;
  const int qt = bid & 31;

  for (int i = tid; i < 2048; i += 256) cs_lds[i] = 0.0f;

  // Q fragments: fp32 global -> bf16 regs, fold 1/sqrt(64). 16 rows per wave.
  const float* qg = qf + ((size_t)bh * L_ + (size_t)qt * 64 + w * 16) * D_;
  bf16x8 aq[2];
#pragma unroll
  for (int h = 0; h < 2; ++h) {
    const float* r = qg + lc * D_ + h * 32 + lg * 8;
    float4 f0 = *reinterpret_cast<const float4*>(r);
    float4 f1 = *reinterpret_cast<const float4*>(r + 4);
    bf16x8 a;
    a[0] = (short)f2bf(f0.x * 0.125f); a[1] = (short)f2bf(f0.y * 0.125f);
    a[2] = (short)f2bf(f0.z * 0.125f); a[3] = (short)f2bf(f0.w * 0.125f);
    a[4] = (short)f2bf(f1.x * 0.125f); a[5] = (short)f2bf(f1.y * 0.125f);
    a[6] = (short)f2bf(f1.z * 0.125f); a[7] = (short)f2bf(f1.w * 0.125f);
    aq[h] = a;
  }

  const unsigned short* ktiles = wkf + (size_t)bh * NKT * 4096;
  const unsigned short* vg = wvf + (size_t)bh * NKT * 4096 + lane * 8;
  const int ub = w * 1024;  // this wave's 2KB staging chunk (ushorts)

  __syncthreads();  // cs_lds init visible

  // ---------------- sweep 1: row sums of exp(s), K staged ----------------
  float lp[4] = {0.f, 0.f, 0.f, 0.f};
  {
    const unsigned short* g = ktiles + ub + lane * 8;
    gload_lds16(g, &kb[0][ub]);
    gload_lds16(g + 512, &kb[0][ub + 512]);
  }
  int b = 0;
#pragma unroll 1
  for (int kt = 0; kt < NKT; ++kt) {
    if (kt + 1 < NKT) {
      const unsigned short* g = ktiles + (kt + 1) * 4096 + ub + lane * 8;
      gload_lds16(g, &kb[b ^ 1][ub]);
      gload_lds16(g + 512, &kb[b ^ 1][ub + 512]);
      asm volatile("s_waitcnt vmcnt(2)" ::: "memory");  // tile kt staged
    } else {
      asm volatile("s_waitcnt vmcnt(0)" ::: "memory");
    }
    BAR();  // entry: kb[b] ready for all waves

    const unsigned short* kbl = kb[b] + lane * 8;
    f32x4 s[4];
#pragma unroll
    for (int t = 0; t < 4; ++t) s[t] = f32x4{0.f, 0.f, 0.f, 0.f};
#pragma unroll
    for (int t = 0; t < 4; ++t) {
      bf16x8 b0 = *reinterpret_cast<const bf16x8*>(kbl + (t * 2 + 0) * 512);
      bf16x8 b1 = *reinterpret_cast<const bf16x8*>(kbl + (t * 2 + 1) * 512);
      s[t] = __builtin_amdgcn_mfma_f32_16x16x32_bf16(aq[0], b0, s[t], 0, 0, 0);
      s[t] = __builtin_amdgcn_mfma_f32_16x16x32_bf16(aq[1], b1, s[t], 0, 0, 0);
    }
#pragma unroll
    for (int t = 0; t < 4; ++t)
#pragma unroll
      for (int r = 0; r < 4; ++r) lp[r] += __expf(s[t][r]);

    asm volatile("s_waitcnt lgkmcnt(0)" ::: "memory");  // my kb reads retired
    BAR();  // exit: all waves done with kb[b]
    b ^= 1;
  }

  // prefetch tile 0 for sweep 2 while reducing linv (b == 0 after 32 flips)
  {
    const unsigned short* g = ktiles + ub + lane * 8;
    gload_lds16(g, &kb[0][ub]);
    gload_lds16(g + 512, &kb[0][ub + 512]);
  }
  float linv[4];
#pragma unroll
  for (int r = 0; r < 4; ++r) {
    float v = lp[r];
    v += __shfl_xor(v, 1);
    v += __shfl_xor(v, 2);
    v += __shfl_xor(v, 4);
    v += __shfl_xor(v, 8);
    linv[r] = 1.0f / v;
  }

  // ---------------- sweep 2: P writes + colsum + P@V ----------------
  f32x4 o[4];
#pragma unroll
  for (int dt = 0; dt < 4; ++dt) o[dt] = f32x4{0.f, 0.f, 0.f, 0.f};

  float* scoreW = score + ((size_t)bh * L_ + (size_t)qt * 64 + w * 16) * L_;
  char* pw = (char*)ps[w];
  b = 0;

#pragma unroll 1
  for (int kt = 0; kt < NKT; ++kt) {
    if (kt + 1 < NKT) {
      const unsigned short* g = ktiles + (kt + 1) * 4096 + ub + lane * 8;
      gload_lds16(g, &kb[b ^ 1][ub]);
      gload_lds16(g + 512, &kb[b ^ 1][ub + 512]);
    }
    // outstanding (old->new): gl(kt)2 | st(kt-1)4 | gl(kt+1)2
    if (kt == 0)               asm volatile("s_waitcnt vmcnt(2)" ::: "memory");
    else if (kt + 1 < NKT)     asm volatile("s_waitcnt vmcnt(6)" ::: "memory");
    else                       asm volatile("s_waitcnt vmcnt(4)" ::: "memory");
    BAR();  // entry: kb[b] ready

    const unsigned short* kbl = kb[b] + lane * 8;
    f32x4 s[4];
#pragma unroll
    for (int t = 0; t < 4; ++t) s[t] = f32x4{0.f, 0.f, 0.f, 0.f};
#pragma unroll
    for (int t = 0; t < 4; ++t) {
      bf16x8 b0 = *reinterpret_cast<const bf16x8*>(kbl + (t * 2 + 0) * 512);
      bf16x8 b1 = *reinterpret_cast<const bf16x8*>(kbl + (t * 2 + 1) * 512);
      s[t] = __builtin_amdgcn_mfma_f32_16x16x32_bf16(aq[0], b0, s[t], 0, 0, 0);
      s[t] = __builtin_amdgcn_mfma_f32_16x16x32_bf16(aq[1], b1, s[t], 0, 0, 0);
    }

    // P = exp(s)*linv -> bf16 stage (per-wave LDS, swizzled) + column partials
    float ct[4] = {0.f, 0.f, 0.f, 0.f};
#pragma unroll
    for (int t = 0; t < 4; ++t)
#pragma unroll
      for (int r = 0; r < 4; ++r) {
        float p = __expf(s[t][r]) * linv[r];
        ct[t] += p;
        int prow = lg * 4 + r;
        unsigned off = ((unsigned)(prow * 128 + (t * 16 + lc) * 2)) ^ (((unsigned)(prow & 7)) << 4);
        *reinterpret_cast<unsigned short*>(pw + off) = f2bf(p);
      }

    // colsum: stagger t by wave to avoid cross-wave same-address LDS atomics
#pragma unroll
    for (int t = 0; t < 4; ++t) {
      int tt = (t + w) & 3;
      float c = ct[tt];
      c += __shfl_xor(c, 16);
      c += __shfl_xor(c, 32);
      if (lane < 16) atomicAdd(&cs_lds[kt * 64 + tt * 16 + lane], c);
    }

    // P@V: A from per-wave stage (same-wave LDS W->R), B direct from L2 frag tiles
#pragma unroll
    for (int kk = 0; kk < 2; ++kk) {
      unsigned o0 = ((unsigned)(lc * 128 + kk * 64 + lg * 16)) ^ (((unsigned)(lc & 7)) << 4);
      bf16x8 pa = *reinterpret_cast<const bf16x8*>(pw + o0);
      const unsigned short* vb = vg + kt * 4096 + kk * 512;
#pragma unroll
      for (int dt = 0; dt < 4; ++dt) {
        bf16x8 bv = *reinterpret_cast<const bf16x8*>(vb + dt * 1024);
        o[dt] = __builtin_amdgcn_mfma_f32_16x16x32_bf16(pa, bv, o[dt], 0, 0, 0);
      }
    }

    // score stores: each instruction covers 8 rows x 128B CONTIGUOUS, plain
    // stores through L2 write-back (NT removed -- the tested variable)
#pragma unroll
    for (int rnd = 0; rnd < 2; ++rnd) {
      int prow = rnd * 8 + (lane >> 3);
      int j = lane & 7;
      unsigned base = (unsigned)(prow * 128);
      unsigned sw = ((unsigned)(prow & 7)) << 4;
#pragma unroll
      for (int h = 0; h < 2; ++h) {
        unsigned off = (base + h * 64 + j * 8) ^ sw;   // 8B read, stays in 16B chunk
        ushort4 p4 = *reinterpret_cast<const ushort4*>(pw + off);
        f32x4 f;
        f[0] = bf2f(p4.x); f[1] = bf2f(p4.y); f[2] = bf2f(p4.z); f[3] = bf2f(p4.w);
        float* sg = scoreW + (size_t)prow * L_ + kt * 64 + h * 32 + j * 4;
        *reinterpret_cast<f32x4*>(sg) = f;
      }
    }

    asm volatile("s_waitcnt lgkmcnt(0)" ::: "memory");  // my kb/ps reads retired
    BAR();  // exit: all waves done with kb[b]
    b ^= 1;
  }

  // O store: stage via kb (free after final BAR), 4KB per wave, then
  // 4x contiguous 1KB float4 store instructions (plain).
  {
    float* ow = reinterpret_cast<float*>(&kb[0][0]) + w * 1024;
#pragma unroll
    for (int dt = 0; dt < 4; ++dt)
#pragma unroll
      for (int r = 0; r < 4; ++r)
        ow[(lg * 4 + r) * 64 + dt * 16 + lc] = o[dt][r];
    float* og = outp + ((size_t)bh * L_ + (size_t)qt * 64 + w * 16) * D_;
#pragma unroll
    for (int it = 0; it < 4; ++it) {
      int i = it * 64 + lane;
      int row = i >> 4, c4 = (i & 15) * 4;
      f32x4 f = *reinterpret_cast<const f32x4*>(ow + row * 64 + c4);
      *reinterpret_cast<f32x4*>(og + (size_t)row * D_ + c4) = f;
    }
  }

  // flush block-local colsums
  __syncthreads();
  for (int i = tid; i < L_; i += 256) atomicAdd(&colsum[bh * L_ + i], cs_lds[i]);
}

// Drop columns whose mean <= 1e-5 (expected: none for this data).
__global__ void mask_fix(float* __restrict__ outp, float* __restrict__ score,
                         const float* __restrict__ colsum, const float* __restrict__ v) {
  __shared__ int drop_list[2048];
  __shared__ int ndrop;
  int bh = blockIdx.x;
  if (threadIdx.x == 0) ndrop = 0;
  __syncthreads();
  for (int c = threadIdx.x; c < L_; c += 256) {
    float mean = colsum[bh * L_ + c] * (1.0f / 2048.0f);
    if (!(mean > 1e-5f)) {
      int idx = atomicAdd(&ndrop, 1);
      drop_list[idx] = c;
    }
  }
  __syncthreads();
  int nd = ndrop;
  if (nd == 0) return;
  float* sc = score + (size_t)bh * L_ * L_;
  float* ob = outp + (size_t)bh * L_ * D_;
  const float* vb = v + (size_t)bh * L_ * D_;
  for (int i = 0; i < nd; ++i) {
    int k = drop_list[i];
    for (int idx = threadIdx.x; idx < L_ * D_; idx += 256) {
      int q = idx >> 6, d = idx & 63;
      ob[q * D_ + d] -= sc[(size_t)q * L_ + k] * vb[k * D_ + d];
    }
    __syncthreads();
  }
  for (int i = 0; i < nd; ++i) {
    int k = drop_list[i];
    for (int q = threadIdx.x; q < L_; q += 256) sc[(size_t)q * L_ + k] = 0.0f;
  }
}

extern "C" void kernel_launch(void* const* d_in, const int* in_sizes, int n_in,
                              void* d_out, int out_size, void* d_ws, size_t ws_size,
                              hipStream_t stream) {
  const float* q = (const float*)d_in[0];
  const float* k = (const float*)d_in[1];
  const float* v = (const float*)d_in[2];
  float* outp = (float*)d_out;
  float* score = outp + (size_t)BH_ * L_ * D_;

  unsigned short* wkf = (unsigned short*)d_ws;
  unsigned short* wvf = wkf + (size_t)BH_ * L_ * D_;
  float* colsum = (float*)(wvf + (size_t)BH_ * L_ * D_);

  prep<<<BH_ * NKT, 256, 0, stream>>>(k, v, wkf, wvf, colsum);
  attn_main<<<1024, 256, 0, stream>>>(q, wkf, wvf, outp, score, colsum);
  mask_fix<<<BH_, 256, 0, stream>>>(outp, score, colsum, v);
}

// Round 12
// 266.749 us; speedup vs baseline: 1.0814x; 1.0814x over previous
//
#include <hip/hip_runtime.h>

// B=2,H=16,L=2048,D=64 attention, outputs (out[B,H,L,D], score[B,H,L,L]) fp32.
// Floor: write score/out 554MB + read QKV ~50MB ~ 90us at 6.7 TB/s.
//
// v9: L2-independent kernel + plain stores.
// Evidence: v8 (plain stores, V direct from L2) = 288us -- score stream
// write-allocates in L2, evicts V, V reads hit HBM. v7 (NT, V direct) =
// 192.7us -- NT protects L2 but NT store path caps ~3.5-4 TB/s. Harness
// fills prove plain stores stream at 6.7 TB/s when L2 has no competing
// reads. So: stage BOTH K and V in LDS (gload_lds dbuf, fragment-linear),
// colsum via direct global atomics (drops cs_lds -> LDS=40960B exactly,
// keeps 4 blocks/CU), plain f32x4 stores for score/O.

#define L_ 2048
#define D_ 64
#define BH_ 32
#define NKT 32

typedef __attribute__((ext_vector_type(8))) short bf16x8;
typedef __attribute__((ext_vector_type(4))) float f32x4;

__device__ __forceinline__ unsigned short f2bf(float f) {
  unsigned u = __builtin_bit_cast(unsigned, f);
  u = (u + 0x7FFFu + ((u >> 16) & 1u)) >> 16;  // RNE
  return (unsigned short)u;
}
__device__ __forceinline__ float bf2f(unsigned short h) {
  unsigned u = ((unsigned)h) << 16;
  return __builtin_bit_cast(float, u);
}
__device__ __forceinline__ void gload_lds16(const void* g, void* l) {
  __builtin_amdgcn_global_load_lds((const __attribute__((address_space(1))) void*)g,
                                   (__attribute__((address_space(3))) void*)l, 16, 0, 0);
}
#define BAR() asm volatile("s_barrier" ::: "memory")

// prep: per 64x64 tile (1024 tiles = bh*32+kt):
//   K -> bf16 fragment-linear tile: el off = (t*2+h)*512 + lg*128 + lc*8 + j
//   V -> VT (transpose) in the same fragment-linear layout (rows=d, cols=k).
// Also zeroes colsum (blocks 0..63).
__global__ void prep(const float* __restrict__ k, const float* __restrict__ v,
                     unsigned short* __restrict__ wkf, unsigned short* __restrict__ wvf,
                     float* __restrict__ colsum) {
  __shared__ unsigned short t_[64][65];
  const int bid = blockIdx.x, tid = threadIdx.x;

  if (bid < 64) {
    float* cz = colsum + bid * 1024;
    for (int i = tid; i < 1024; i += 256) cz[i] = 0.0f;
  }

  // K tile -> fragment layout
  const float* ks = k + (size_t)bid * 64 * D_;
  unsigned short* kd = wkf + (size_t)bid * 4096;
#pragma unroll
  for (int it = 0; it < 2; ++it) {
    int e8 = it * 256 + tid;      // [0,512)
    int r = e8 >> 3;              // row 0..63
    int c0 = (e8 & 7) * 8;        // col 0,8,..,56
    float4 f0 = *reinterpret_cast<const float4*>(ks + r * D_ + c0);
    float4 f1 = *reinterpret_cast<const float4*>(ks + r * D_ + c0 + 4);
    int t = r >> 4, lc = r & 15, h = c0 >> 5, lg = (c0 & 31) >> 3;
    unsigned short* p = kd + (t * 2 + h) * 512 + lg * 128 + lc * 8;
    ushort4 u0{f2bf(f0.x), f2bf(f0.y), f2bf(f0.z), f2bf(f0.w)};
    ushort4 u1{f2bf(f1.x), f2bf(f1.y), f2bf(f1.z), f2bf(f1.w)};
    *reinterpret_cast<ushort4*>(p) = u0;
    *reinterpret_cast<ushort4*>(p + 4) = u1;
  }

  // V tile -> LDS transpose -> fragment layout (rows=d, cols=k)
  const float* vs = v + (size_t)bid * 64 * D_;
#pragma unroll
  for (int it = 0; it < 4; ++it) {
    int e4 = tid + it * 256;
    int r = e4 >> 4, c = (e4 & 15) << 2;
    float4 f = *reinterpret_cast<const float4*>(vs + r * D_ + c);
    t_[r][c + 0] = f2bf(f.x);
    t_[r][c + 1] = f2bf(f.y);
    t_[r][c + 2] = f2bf(f.z);
    t_[r][c + 3] = f2bf(f.w);
  }
  __syncthreads();
  unsigned short* vd = wvf + (size_t)bid * 4096;
#pragma unroll
  for (int it = 0; it < 2; ++it) {
    int e8 = it * 256 + tid;
    int d = e8 >> 3;             // output row (d-dim)
    int k0 = (e8 & 7) * 8;       // output col (k within tile)
    int t = d >> 4, lc = d & 15, h = k0 >> 5, lg = (k0 & 31) >> 3;
    ushort4 u0{t_[k0 + 0][d], t_[k0 + 1][d], t_[k0 + 2][d], t_[k0 + 3][d]};
    ushort4 u1{t_[k0 + 4][d], t_[k0 + 5][d], t_[k0 + 6][d], t_[k0 + 7][d]};
    unsigned short* p = vd + (t * 2 + h) * 512 + lg * 128 + lc * 8;
    *reinterpret_cast<ushort4*>(p) = u0;
    *reinterpret_cast<ushort4*>(p + 4) = u1;
  }
}

__launch_bounds__(256, 4)
__global__ void attn_main(const float* __restrict__ qf,
                          const unsigned short* __restrict__ wkf,
                          const unsigned short* __restrict__ wvf,
                          float* __restrict__ outp,
                          float* __restrict__ score,
                          float* __restrict__ colsum) {
  __shared__ __align__(16) unsigned short kbK[2][4096];  // K tile dbuf; reused as O stage
  __shared__ __align__(16) unsigned short kbV[2][4096];  // V tile dbuf
  __shared__ __align__(16) unsigned short ps[4][1024];   // per-wave 16x64 bf16 swizzled

  const int tid = threadIdx.x;
  const int w = tid >> 6, lane = tid & 63;
  const int lg = lane >> 4, lc = lane & 15;

  // XCD-chunked swizzle: 1024 blocks -> 128 consecutive per XCD (4 bh per XCD)
  const int bid = (blockIdx.x & 7) * 128 + (blockIdx.x >> 3);
  const int bh = bid >> 5;
  const int qt = bid & 31;

  // Q fragments: fp32 global -> bf16 regs, fold 1/sqrt(64). 16 rows per wave.
  const float* qg = qf + ((size_t)bh * L_ + (size_t)qt * 64 + w * 16) * D_;
  bf16x8 aq[2];
#pragma unroll
  for (int h = 0; h < 2; ++h) {
    const float* r = qg + lc * D_ + h * 32 + lg * 8;
    float4 f0 = *reinterpret_cast<const float4*>(r);
    float4 f1 = *reinterpret_cast<const float4*>(r + 4);
    bf16x8 a;
    a[0] = (short)f2bf(f0.x * 0.125f); a[1] = (short)f2bf(f0.y * 0.125f);
    a[2] = (short)f2bf(f0.z * 0.125f); a[3] = (short)f2bf(f0.w * 0.125f);
    a[4] = (short)f2bf(f1.x * 0.125f); a[5] = (short)f2bf(f1.y * 0.125f);
    a[6] = (short)f2bf(f1.z * 0.125f); a[7] = (short)f2bf(f1.w * 0.125f);
    aq[h] = a;
  }

  const unsigned short* ktiles = wkf + (size_t)bh * NKT * 4096;
  const unsigned short* vtiles = wvf + (size_t)bh * NKT * 4096;
  const int ub = w * 1024;  // this wave's 2KB staging chunk (ushorts)

  // ---------------- sweep 1: row sums of exp(s), K staged ----------------
  float lp[4] = {0.f, 0.f, 0.f, 0.f};
  {
    const unsigned short* g = ktiles + ub + lane * 8;
    gload_lds16(g, &kbK[0][ub]);
    gload_lds16(g + 512, &kbK[0][ub + 512]);
  }
  int b = 0;
#pragma unroll 1
  for (int kt = 0; kt < NKT; ++kt) {
    if (kt + 1 < NKT) {
      const unsigned short* g = ktiles + (kt + 1) * 4096 + ub + lane * 8;
      gload_lds16(g, &kbK[b ^ 1][ub]);
      gload_lds16(g + 512, &kbK[b ^ 1][ub + 512]);
      asm volatile("s_waitcnt vmcnt(2)" ::: "memory");  // tile kt staged
    } else {
      asm volatile("s_waitcnt vmcnt(0)" ::: "memory");
    }
    BAR();  // entry: kbK[b] ready for all waves

    const unsigned short* kbl = kbK[b] + lane * 8;
    f32x4 s[4];
#pragma unroll
    for (int t = 0; t < 4; ++t) s[t] = f32x4{0.f, 0.f, 0.f, 0.f};
#pragma unroll
    for (int t = 0; t < 4; ++t) {
      bf16x8 b0 = *reinterpret_cast<const bf16x8*>(kbl + (t * 2 + 0) * 512);
      bf16x8 b1 = *reinterpret_cast<const bf16x8*>(kbl + (t * 2 + 1) * 512);
      s[t] = __builtin_amdgcn_mfma_f32_16x16x32_bf16(aq[0], b0, s[t], 0, 0, 0);
      s[t] = __builtin_amdgcn_mfma_f32_16x16x32_bf16(aq[1], b1, s[t], 0, 0, 0);
    }
#pragma unroll
    for (int t = 0; t < 4; ++t)
#pragma unroll
      for (int r = 0; r < 4; ++r) lp[r] += __expf(s[t][r]);

    asm volatile("s_waitcnt lgkmcnt(0)" ::: "memory");  // my kbK reads retired
    BAR();  // exit: all waves done with kbK[b]
    b ^= 1;
  }

  // prefetch K+V tile 0 for sweep 2 while reducing linv (b==0 after 32 flips)
  {
    const unsigned short* gk = ktiles + ub + lane * 8;
    const unsigned short* gv = vtiles + ub + lane * 8;
    gload_lds16(gk, &kbK[0][ub]);
    gload_lds16(gk + 512, &kbK[0][ub + 512]);
    gload_lds16(gv, &kbV[0][ub]);
    gload_lds16(gv + 512, &kbV[0][ub + 512]);
  }
  float linv[4];
#pragma unroll
  for (int r = 0; r < 4; ++r) {
    float v = lp[r];
    v += __shfl_xor(v, 1);
    v += __shfl_xor(v, 2);
    v += __shfl_xor(v, 4);
    v += __shfl_xor(v, 8);
    linv[r] = 1.0f / v;
  }

  // ---------------- sweep 2: P writes + colsum + P@V ----------------
  f32x4 o[4];
#pragma unroll
  for (int dt = 0; dt < 4; ++dt) o[dt] = f32x4{0.f, 0.f, 0.f, 0.f};

  float* scoreW = score + ((size_t)bh * L_ + (size_t)qt * 64 + w * 16) * L_;
  float* csb = colsum + bh * L_;
  char* pw = (char*)ps[w];
  b = 0;

#pragma unroll 1
  for (int kt = 0; kt < NKT; ++kt) {
    if (kt + 1 < NKT) {
      const unsigned short* gk = ktiles + (kt + 1) * 4096 + ub + lane * 8;
      const unsigned short* gv = vtiles + (kt + 1) * 4096 + ub + lane * 8;
      gload_lds16(gk, &kbK[b ^ 1][ub]);
      gload_lds16(gk + 512, &kbK[b ^ 1][ub + 512]);
      gload_lds16(gv, &kbV[b ^ 1][ub]);
      gload_lds16(gv + 512, &kbV[b ^ 1][ub + 512]);
    }
    // FIFO younger-than-gl(kt): kt=0 -> gl(1)=4; steady -> at(4)+st(4)+gl(4)=12;
    // last -> at(4)+st(4)=8
    if (kt == 0)               asm volatile("s_waitcnt vmcnt(4)" ::: "memory");
    else if (kt + 1 < NKT)     asm volatile("s_waitcnt vmcnt(12)" ::: "memory");
    else                       asm volatile("s_waitcnt vmcnt(8)" ::: "memory");
    BAR();  // entry: kbK[b]/kbV[b] ready

    const unsigned short* kbl = kbK[b] + lane * 8;
    const unsigned short* vbl = kbV[b] + lane * 8;
    f32x4 s[4];
#pragma unroll
    for (int t = 0; t < 4; ++t) s[t] = f32x4{0.f, 0.f, 0.f, 0.f};
#pragma unroll
    for (int t = 0; t < 4; ++t) {
      bf16x8 b0 = *reinterpret_cast<const bf16x8*>(kbl + (t * 2 + 0) * 512);
      bf16x8 b1 = *reinterpret_cast<const bf16x8*>(kbl + (t * 2 + 1) * 512);
      s[t] = __builtin_amdgcn_mfma_f32_16x16x32_bf16(aq[0], b0, s[t], 0, 0, 0);
      s[t] = __builtin_amdgcn_mfma_f32_16x16x32_bf16(aq[1], b1, s[t], 0, 0, 0);
    }

    // P = exp(s)*linv -> bf16 stage (per-wave LDS, swizzled) + column partials
    float ct[4] = {0.f, 0.f, 0.f, 0.f};
#pragma unroll
    for (int t = 0; t < 4; ++t)
#pragma unroll
      for (int r = 0; r < 4; ++r) {
        float p = __expf(s[t][r]) * linv[r];
        ct[t] += p;
        int prow = lg * 4 + r;
        unsigned off = ((unsigned)(prow * 128 + (t * 16 + lc) * 2)) ^ (((unsigned)(prow & 7)) << 4);
        *reinterpret_cast<unsigned short*>(pw + off) = f2bf(p);
      }

    // colsum: direct global atomics, staggered by wave (t+w)&3
#pragma unroll
    for (int t = 0; t < 4; ++t) {
      int tt = (t + w) & 3;
      float c = ct[tt];
      c += __shfl_xor(c, 16);
      c += __shfl_xor(c, 32);
      if (lane < 16) atomicAdd(csb + kt * 64 + tt * 16 + lane, c);
    }

    // P@V: A from per-wave stage (same-wave LDS W->R), B from staged V tile
#pragma unroll
    for (int kk = 0; kk < 2; ++kk) {
      unsigned o0 = ((unsigned)(lc * 128 + kk * 64 + lg * 16)) ^ (((unsigned)(lc & 7)) << 4);
      bf16x8 pa = *reinterpret_cast<const bf16x8*>(pw + o0);
#pragma unroll
      for (int dt = 0; dt < 4; ++dt) {
        bf16x8 bv = *reinterpret_cast<const bf16x8*>(vbl + (dt * 2 + kk) * 512);
        o[dt] = __builtin_amdgcn_mfma_f32_16x16x32_bf16(pa, bv, o[dt], 0, 0, 0);
      }
    }

    // score stores: plain f32x4 through L2 write-back (L2 now holds no
    // needed data -- K/V staged), each instr = 8 rows x 128B contiguous
#pragma unroll
    for (int rnd = 0; rnd < 2; ++rnd) {
      int prow = rnd * 8 + (lane >> 3);
      int j = lane & 7;
      unsigned base = (unsigned)(prow * 128);
      unsigned sw = ((unsigned)(prow & 7)) << 4;
#pragma unroll
      for (int h = 0; h < 2; ++h) {
        unsigned off = (base + h * 64 + j * 8) ^ sw;   // 8B read, stays in 16B chunk
        ushort4 p4 = *reinterpret_cast<const ushort4*>(pw + off);
        f32x4 f;
        f[0] = bf2f(p4.x); f[1] = bf2f(p4.y); f[2] = bf2f(p4.z); f[3] = bf2f(p4.w);
        float* sg = scoreW + (size_t)prow * L_ + kt * 64 + h * 32 + j * 4;
        *reinterpret_cast<f32x4*>(sg) = f;
      }
    }

    asm volatile("s_waitcnt lgkmcnt(0)" ::: "memory");  // my kbK/kbV/ps reads retired
    BAR();  // exit: all waves done with buffers
    b ^= 1;
  }

  // O store: stage via kbK (free after final BAR), 4KB per wave, then
  // 4x contiguous 1KB float4 store instructions (plain).
  {
    float* ow = reinterpret_cast<float*>(&kbK[0][0]) + w * 1024;
#pragma unroll
    for (int dt = 0; dt < 4; ++dt)
#pragma unroll
      for (int r = 0; r < 4; ++r)
        ow[(lg * 4 + r) * 64 + dt * 16 + lc] = o[dt][r];
    float* og = outp + ((size_t)bh * L_ + (size_t)qt * 64 + w * 16) * D_;
#pragma unroll
    for (int it = 0; it < 4; ++it) {
      int i = it * 64 + lane;
      int row = i >> 4, c4 = (i & 15) * 4;
      f32x4 f = *reinterpret_cast<const f32x4*>(ow + row * 64 + c4);
      *reinterpret_cast<f32x4*>(og + (size_t)row * D_ + c4) = f;
    }
  }
}

// Drop columns whose mean <= 1e-5 (expected: none for this data).
__global__ void mask_fix(float* __restrict__ outp, float* __restrict__ score,
                         const float* __restrict__ colsum, const float* __restrict__ v) {
  __shared__ int drop_list[2048];
  __shared__ int ndrop;
  int bh = blockIdx.x;
  if (threadIdx.x == 0) ndrop = 0;
  __syncthreads();
  for (int c = threadIdx.x; c < L_; c += 256) {
    float mean = colsum[bh * L_ + c] * (1.0f / 2048.0f);
    if (!(mean > 1e-5f)) {
      int idx = atomicAdd(&ndrop, 1);
      drop_list[idx] = c;
    }
  }
  __syncthreads();
  int nd = ndrop;
  if (nd == 0) return;
  float* sc = score + (size_t)bh * L_ * L_;
  float* ob = outp + (size_t)bh * L_ * D_;
  const float* vb = v + (size_t)bh * L_ * D_;
  for (int i = 0; i < nd; ++i) {
    int k = drop_list[i];
    for (int idx = threadIdx.x; idx < L_ * D_; idx += 256) {
      int q = idx >> 6, d = idx & 63;
      ob[q * D_ + d] -= sc[(size_t)q * L_ + k] * vb[k * D_ + d];
    }
    __syncthreads();
  }
  for (int i = 0; i < nd; ++i) {
    int k = drop_list[i];
    for (int q = threadIdx.x; q < L_; q += 256) sc[(size_t)q * L_ + k] = 0.0f;
  }
}

extern "C" void kernel_launch(void* const* d_in, const int* in_sizes, int n_in,
                              void* d_out, int out_size, void* d_ws, size_t ws_size,
                              hipStream_t stream) {
  const float* q = (const float*)d_in[0];
  const float* k = (const float*)d_in[1];
  const float* v = (const float*)d_in[2];
  float* outp = (float*)d_out;
  float* score = outp + (size_t)BH_ * L_ * D_;

  unsigned short* wkf = (unsigned short*)d_ws;
  unsigned short* wvf = wkf + (size_t)BH_ * L_ * D_;
  float* colsum = (float*)(wvf + (size_t)BH_ * L_ * D_);

  prep<<<BH_ * NKT, 256, 0, stream>>>(k, v, wkf, wvf, colsum);
  attn_main<<<1024, 256, 0, stream>>>(q, wkf, wvf, outp, score, colsum);
  mask_fix<<<BH_, 256, 0, stream>>>(outp, score, colsum, v);
}

// Round 13
// 170.752 us; speedup vs baseline: 1.6893x; 1.5622x over previous
//
#include <hip/hip_runtime.h>

// B=2,H=16,L=2048,D=64 attention, outputs (out[B,H,L,D], score[B,H,L,L]) fp32.
// Floor: write score/out 554MB + read QKV ~50MB ~ 90us at 6.7 TB/s.
//
// v10 = round-5 barrier-free structure (direct-L2 K/V frag reads, 4 blk/CU,
// QT=64) + NT stores (v11/v12 proved plain stores lose 70-95us to L2 write-
// allocate thrash) + contiguous 128B chunks (v7) + NEW: kt-PAIR batched
// stores. Both P halves staged in LDS, then per row-group the 4 chunk
// stores (4x128B = 512B/row) issue back-to-back so the HBM write combiner
// sees 512B bursts instead of 128B column stripes at 8KB stride.

#define L_ 2048
#define D_ 64
#define BH_ 32
#define NKT 32

typedef __attribute__((ext_vector_type(8))) short bf16x8;
typedef __attribute__((ext_vector_type(4))) float f32x4;

__device__ __forceinline__ unsigned short f2bf(float f) {
  unsigned u = __builtin_bit_cast(unsigned, f);
  u = (u + 0x7FFFu + ((u >> 16) & 1u)) >> 16;  // RNE
  return (unsigned short)u;
}
__device__ __forceinline__ float bf2f(unsigned short h) {
  unsigned u = ((unsigned)h) << 16;
  return __builtin_bit_cast(float, u);
}

// prep: per 64x64 tile (1024 tiles = bh*32+kt):
//   K -> bf16 fragment-linear tile: el off = (t*2+h)*512 + lg*128 + lc*8 + j
//   V -> VT (transpose) in the same fragment-linear layout (rows=d, cols=k).
// Also zeroes colsum (blocks 0..63).
__global__ void prep(const float* __restrict__ k, const float* __restrict__ v,
                     unsigned short* __restrict__ wkf, unsigned short* __restrict__ wvf,
                     float* __restrict__ colsum) {
  __shared__ unsigned short t_[64][65];
  const int bid = blockIdx.x, tid = threadIdx.x;

  if (bid < 64) {
    float* cz = colsum + bid * 1024;
    for (int i = tid; i < 1024; i += 256) cz[i] = 0.0f;
  }

  // K tile -> fragment layout
  const float* ks = k + (size_t)bid * 64 * D_;
  unsigned short* kd = wkf + (size_t)bid * 4096;
#pragma unroll
  for (int it = 0; it < 2; ++it) {
    int e8 = it * 256 + tid;      // [0,512)
    int r = e8 >> 3;              // row 0..63
    int c0 = (e8 & 7) * 8;        // col 0,8,..,56
    float4 f0 = *reinterpret_cast<const float4*>(ks + r * D_ + c0);
    float4 f1 = *reinterpret_cast<const float4*>(ks + r * D_ + c0 + 4);
    int t = r >> 4, lc = r & 15, h = c0 >> 5, lg = (c0 & 31) >> 3;
    unsigned short* p = kd + (t * 2 + h) * 512 + lg * 128 + lc * 8;
    ushort4 u0{f2bf(f0.x), f2bf(f0.y), f2bf(f0.z), f2bf(f0.w)};
    ushort4 u1{f2bf(f1.x), f2bf(f1.y), f2bf(f1.z), f2bf(f1.w)};
    *reinterpret_cast<ushort4*>(p) = u0;
    *reinterpret_cast<ushort4*>(p + 4) = u1;
  }

  // V tile -> LDS transpose -> fragment layout (rows=d, cols=k)
  const float* vs = v + (size_t)bid * 64 * D_;
#pragma unroll
  for (int it = 0; it < 4; ++it) {
    int e4 = tid + it * 256;
    int r = e4 >> 4, c = (e4 & 15) << 2;
    float4 f = *reinterpret_cast<const float4*>(vs + r * D_ + c);
    t_[r][c + 0] = f2bf(f.x);
    t_[r][c + 1] = f2bf(f.y);
    t_[r][c + 2] = f2bf(f.z);
    t_[r][c + 3] = f2bf(f.w);
  }
  __syncthreads();
  unsigned short* vd = wvf + (size_t)bid * 4096;
#pragma unroll
  for (int it = 0; it < 2; ++it) {
    int e8 = it * 256 + tid;
    int d = e8 >> 3;             // output row (d-dim)
    int k0 = (e8 & 7) * 8;       // output col (k within tile)
    int t = d >> 4, lc = d & 15, h = k0 >> 5, lg = (k0 & 31) >> 3;
    ushort4 u0{t_[k0 + 0][d], t_[k0 + 1][d], t_[k0 + 2][d], t_[k0 + 3][d]};
    ushort4 u1{t_[k0 + 4][d], t_[k0 + 5][d], t_[k0 + 6][d], t_[k0 + 7][d]};
    unsigned short* p = vd + (t * 2 + h) * 512 + lg * 128 + lc * 8;
    *reinterpret_cast<ushort4*>(p) = u0;
    *reinterpret_cast<ushort4*>(p + 4) = u1;
  }
}

__launch_bounds__(256, 4)
__global__ void attn_main(const float* __restrict__ qf,
                          const unsigned short* __restrict__ wkf,
                          const unsigned short* __restrict__ wvf,
                          float* __restrict__ outp,
                          float* __restrict__ score,
                          float* __restrict__ colsum) {
  __shared__ __align__(16) unsigned short ps[4][2][1024];  // per-wave P stage, 2 kt halves
  __shared__ float cs_lds[2048];                           // block-local column sums

  const int tid = threadIdx.x;
  const int w = tid >> 6, lane = tid & 63;
  const int lg = lane >> 4, lc = lane & 15;

  // XCD-chunked swizzle: 1024 blocks -> 128 consecutive per XCD (4 bh per XCD)
  const int bid = (blockIdx.x & 7) * 128 + (blockIdx.x >> 3);
  const int bh = bid >> 5;
  const int qt = bid & 31;

  for (int i = tid; i < 2048; i += 256) cs_lds[i] = 0.0f;

  // Q fragments: fp32 global -> bf16 regs, fold 1/sqrt(64). 16 rows per wave.
  const float* qg = qf + ((size_t)bh * L_ + (size_t)qt * 64 + w * 16) * D_;
  bf16x8 aq[2];
#pragma unroll
  for (int h = 0; h < 2; ++h) {
    const float* r = qg + lc * D_ + h * 32 + lg * 8;
    float4 f0 = *reinterpret_cast<const float4*>(r);
    float4 f1 = *reinterpret_cast<const float4*>(r + 4);
    bf16x8 a;
    a[0] = (short)f2bf(f0.x * 0.125f); a[1] = (short)f2bf(f0.y * 0.125f);
    a[2] = (short)f2bf(f0.z * 0.125f); a[3] = (short)f2bf(f0.w * 0.125f);
    a[4] = (short)f2bf(f1.x * 0.125f); a[5] = (short)f2bf(f1.y * 0.125f);
    a[6] = (short)f2bf(f1.z * 0.125f); a[7] = (short)f2bf(f1.w * 0.125f);
    aq[h] = a;
  }

  __syncthreads();  // cs_lds init visible (only barrier until final flush)

  const unsigned short* kg = wkf + (size_t)bh * NKT * 4096 + lg * 128 + lc * 8;
  const unsigned short* vg = wvf + (size_t)bh * NKT * 4096 + lg * 128 + lc * 8;

  // ---------------- sweep 1: row sums of exp(s) (no max) ----------------
  float lp[4] = {0.f, 0.f, 0.f, 0.f};

#pragma unroll 2
  for (int kt = 0; kt < NKT; ++kt) {
    const unsigned short* kb = kg + kt * 4096;
    f32x4 s[4];
#pragma unroll
    for (int t = 0; t < 4; ++t) s[t] = f32x4{0.f, 0.f, 0.f, 0.f};
#pragma unroll
    for (int t = 0; t < 4; ++t) {
      bf16x8 b0 = *reinterpret_cast<const bf16x8*>(kb + (t * 2 + 0) * 512);
      bf16x8 b1 = *reinterpret_cast<const bf16x8*>(kb + (t * 2 + 1) * 512);
      s[t] = __builtin_amdgcn_mfma_f32_16x16x32_bf16(aq[0], b0, s[t], 0, 0, 0);
      s[t] = __builtin_amdgcn_mfma_f32_16x16x32_bf16(aq[1], b1, s[t], 0, 0, 0);
    }
#pragma unroll
    for (int t = 0; t < 4; ++t)
#pragma unroll
      for (int r = 0; r < 4; ++r) lp[r] += __expf(s[t][r]);
  }

  float linv[4];
#pragma unroll
  for (int r = 0; r < 4; ++r) {
    float v = lp[r];
    v += __shfl_xor(v, 1);
    v += __shfl_xor(v, 2);
    v += __shfl_xor(v, 4);
    v += __shfl_xor(v, 8);
    linv[r] = 1.0f / v;
  }

  // ---------------- sweep 2: kt-pairs; P stage both halves, burst stores --
  f32x4 o[4];
#pragma unroll
  for (int dt = 0; dt < 4; ++dt) o[dt] = f32x4{0.f, 0.f, 0.f, 0.f};

  float* scoreW = score + ((size_t)bh * L_ + (size_t)qt * 64 + w * 16) * L_;

#pragma unroll 1
  for (int ktp = 0; ktp < NKT / 2; ++ktp) {
#pragma unroll
    for (int half = 0; half < 2; ++half) {
      const int kt = ktp * 2 + half;
      const unsigned short* kb = kg + kt * 4096;
      char* pw = (char*)ps[w][half];

      f32x4 s[4];
#pragma unroll
      for (int t = 0; t < 4; ++t) s[t] = f32x4{0.f, 0.f, 0.f, 0.f};
#pragma unroll
      for (int t = 0; t < 4; ++t) {
        bf16x8 b0 = *reinterpret_cast<const bf16x8*>(kb + (t * 2 + 0) * 512);
        bf16x8 b1 = *reinterpret_cast<const bf16x8*>(kb + (t * 2 + 1) * 512);
        s[t] = __builtin_amdgcn_mfma_f32_16x16x32_bf16(aq[0], b0, s[t], 0, 0, 0);
        s[t] = __builtin_amdgcn_mfma_f32_16x16x32_bf16(aq[1], b1, s[t], 0, 0, 0);
      }

      // P = exp(s)*linv -> bf16 stage + column partials
      float ct[4] = {0.f, 0.f, 0.f, 0.f};
#pragma unroll
      for (int t = 0; t < 4; ++t)
#pragma unroll
        for (int r = 0; r < 4; ++r) {
          float p = __expf(s[t][r]) * linv[r];
          ct[t] += p;
          int prow = lg * 4 + r;
          unsigned off = ((unsigned)(prow * 128 + (t * 16 + lc) * 2)) ^ (((unsigned)(prow & 7)) << 4);
          *reinterpret_cast<unsigned short*>(pw + off) = f2bf(p);
        }

      // colsum: stagger t by wave to reduce cross-wave same-address atomics
#pragma unroll
      for (int t = 0; t < 4; ++t) {
        int tt = (t + w) & 3;
        float c = ct[tt];
        c += __shfl_xor(c, 16);
        c += __shfl_xor(c, 32);
        if (lane < 16) atomicAdd(&cs_lds[kt * 64 + tt * 16 + lane], c);
      }

      // P@V: A from this half's stage, B direct from L2 frag tiles
#pragma unroll
      for (int kk = 0; kk < 2; ++kk) {
        unsigned o0 = ((unsigned)(lc * 128 + kk * 64 + lg * 16)) ^ (((unsigned)(lc & 7)) << 4);
        bf16x8 pa = *reinterpret_cast<const bf16x8*>(pw + o0);
        const unsigned short* vb = vg + kt * 4096 + kk * 512;
#pragma unroll
        for (int dt = 0; dt < 4; ++dt) {
          bf16x8 bv = *reinterpret_cast<const bf16x8*>(vb + dt * 1024);
          o[dt] = __builtin_amdgcn_mfma_f32_16x16x32_bf16(pa, bv, o[dt], 0, 0, 0);
        }
      }
    }

    // burst stores: per row-group, 4 consecutive chunk stores = 512B/row
    // contiguous (chunk c: half=c>>1 buffer, cols (c&1)*32..+32)
#pragma unroll
    for (int rnd = 0; rnd < 2; ++rnd) {
      int prow = rnd * 8 + (lane >> 3);
      int j = lane & 7;
      unsigned base = (unsigned)(prow * 128);
      unsigned sw = ((unsigned)(prow & 7)) << 4;
      float* rowp = scoreW + (size_t)prow * L_ + ktp * 128 + j * 4;
#pragma unroll
      for (int c = 0; c < 4; ++c) {
        const char* pw = (const char*)ps[w][c >> 1];
        unsigned off = (base + (c & 1) * 64 + j * 8) ^ sw;
        ushort4 p4 = *reinterpret_cast<const ushort4*>(pw + off);
        f32x4 f;
        f[0] = bf2f(p4.x); f[1] = bf2f(p4.y); f[2] = bf2f(p4.z); f[3] = bf2f(p4.w);
        __builtin_nontemporal_store(f, reinterpret_cast<f32x4*>(rowp + c * 32));
      }
    }
  }

  // O store: stage via ps (free now), 4KB per wave, then 4x contiguous
  // 1KB f32x4 store instructions, NT.
  {
    float* ow = reinterpret_cast<float*>(&ps[w][0][0]);
#pragma unroll
    for (int dt = 0; dt < 4; ++dt)
#pragma unroll
      for (int r = 0; r < 4; ++r)
        ow[(lg * 4 + r) * 64 + dt * 16 + lc] = o[dt][r];
    float* og = outp + ((size_t)bh * L_ + (size_t)qt * 64 + w * 16) * D_;
#pragma unroll
    for (int it = 0; it < 4; ++it) {
      int i = it * 64 + lane;
      int row = i >> 4, c4 = (i & 15) * 4;
      f32x4 f = *reinterpret_cast<const f32x4*>(ow + row * 64 + c4);
      __builtin_nontemporal_store(f, reinterpret_cast<f32x4*>(og + (size_t)row * D_ + c4));
    }
  }

  // flush block-local colsums
  __syncthreads();
  for (int i = tid; i < L_; i += 256) atomicAdd(&colsum[bh * L_ + i], cs_lds[i]);
}

// Drop columns whose mean <= 1e-5 (expected: none for this data).
__global__ void mask_fix(float* __restrict__ outp, float* __restrict__ score,
                         const float* __restrict__ colsum, const float* __restrict__ v) {
  __shared__ int drop_list[2048];
  __shared__ int ndrop;
  int bh = blockIdx.x;
  if (threadIdx.x == 0) ndrop = 0;
  __syncthreads();
  for (int c = threadIdx.x; c < L_; c += 256) {
    float mean = colsum[bh * L_ + c] * (1.0f / 2048.0f);
    if (!(mean > 1e-5f)) {
      int idx = atomicAdd(&ndrop, 1);
      drop_list[idx] = c;
    }
  }
  __syncthreads();
  int nd = ndrop;
  if (nd == 0) return;
  float* sc = score + (size_t)bh * L_ * L_;
  float* ob = outp + (size_t)bh * L_ * D_;
  const float* vb = v + (size_t)bh * L_ * D_;
  for (int i = 0; i < nd; ++i) {
    int k = drop_list[i];
    for (int idx = threadIdx.x; idx < L_ * D_; idx += 256) {
      int q = idx >> 6, d = idx & 63;
      ob[q * D_ + d] -= sc[(size_t)q * L_ + k] * vb[k * D_ + d];
    }
    __syncthreads();
  }
  for (int i = 0; i < nd; ++i) {
    int k = drop_list[i];
    for (int q = threadIdx.x; q < L_; q += 256) sc[(size_t)q * L_ + k] = 0.0f;
  }
}

extern "C" void kernel_launch(void* const* d_in, const int* in_sizes, int n_in,
                              void* d_out, int out_size, void* d_ws, size_t ws_size,
                              hipStream_t stream) {
  const float* q = (const float*)d_in[0];
  const float* k = (const float*)d_in[1];
  const float* v = (const float*)d_in[2];
  float* outp = (float*)d_out;
  float* score = outp + (size_t)BH_ * L_ * D_;

  unsigned short* wkf = (unsigned short*)d_ws;
  unsigned short* wvf = wkf + (size_t)BH_ * L_ * D_;
  float* colsum = (float*)(wvf + (size_t)BH_ * L_ * D_);

  prep<<<BH_ * NKT, 256, 0, stream>>>(k, v, wkf, wvf, colsum);
  attn_main<<<1024, 256, 0, stream>>>(q, wkf, wvf, outp, score, colsum);
  mask_fix<<<BH_, 256, 0, stream>>>(outp, score, colsum, v);
}